// Round 5
// baseline (237.368 us; speedup 1.0000x reference)
//
#include <hip/hip_runtime.h>

// ---- problem constants ----
#define DM    1024
#define LSEQ  4096
#define BATCH 4
#define MROWS (BATCH * LSEQ)           // 16384 rows
#define MD    ((size_t)MROWS * DM)     // 16,777,216 elems
#define DD    ((size_t)DM * DM)        // 1,048,576 elems
#define CHUNK 32
#define NCH   (LSEQ / CHUNK)           // 128 chunks
#define NCHAIN (BATCH * DM)            // 4096 scan chains

typedef __attribute__((ext_vector_type(4))) float  f32x4;
typedef __attribute__((ext_vector_type(8))) __bf16 bf16x8;
typedef __attribute__((ext_vector_type(4))) __bf16 bf16x4;

__device__ __forceinline__ void gload_lds16(const void* g, void* l) {
  __builtin_amdgcn_global_load_lds(
      (const __attribute__((address_space(1))) void*)g,
      (__attribute__((address_space(3))) void*)l, 16, 0, 0);
}

// ---- fp32 -> bf16 converts ----
__global__ __launch_bounds__(256) void cvt_bf16(const float* __restrict__ in,
                                                __bf16* __restrict__ out) {
  size_t i = ((size_t)blockIdx.x * 256 + threadIdx.x) * 4;
  f32x4 f = *(const f32x4*)(in + i);
  bf16x4 o;
#pragma unroll
  for (int j = 0; j < 4; ++j) o[j] = (__bf16)f[j];
  *(bf16x4*)(out + i) = o;
}

__global__ __launch_bounds__(256) void cvt_w(const float* __restrict__ s0,
                                             const float* __restrict__ s1,
                                             const float* __restrict__ s2,
                                             const float* __restrict__ s3,
                                             __bf16* __restrict__ dst) {
  const float* sp = (blockIdx.z == 0) ? s0 : (blockIdx.z == 1) ? s1
                  : (blockIdx.z == 2) ? s2 : s3;
  size_t i = ((size_t)blockIdx.x * 256 + threadIdx.x) * 4;
  f32x4 f = *(const f32x4*)(sp + i);
  bf16x4 o;
#pragma unroll
  for (int j = 0; j < 4; ++j) o[j] = (__bf16)f[j];
  *(bf16x4*)(dst + (size_t)blockIdx.z * DD + i) = o;
}

// ================= 128x128 double-buffered bf16 NT GEMM =====================
// C[m][n] = sum_k A[m][k] * W[n][k].  M=16384, N=K=1024, BK=32, NT=32.
// 4 waves (2x2, wave tile 64x64), 32KB LDS double-buffer, launch_bounds(256,4)
// -> reg cap 128/wave (acc 64 AGPR + ~60 VGPR) -> 4 blocks/CU, 16 waves/CU.
// Overlap mechanism = INTER-BLOCK: one block's stage/ds_read phase hides
// under another block's MFMAs (m114). Dense 64B-row LDS: a wave's fragment
// read covers a contiguous 1KB region -> conflict-free, no swizzle needed.
// One combined s_waitcnt vmcnt(0) lgkmcnt(0) + s_barrier per K-tile:
//   lgkmcnt(0): our ds_reads of buf[cur] done before kt+1 overwrites it;
//   vmcnt(0):   stages into buf[nxt] arrived before next iter reads it.

__device__ __forceinline__ void stage_tile(const __bf16* __restrict__ base,
                                           __bf16* lds, int k0, int t) {
#pragma unroll
  for (int is = 0; is < 2; ++is) {
    int e = is * 2048 + t * 8;          // element in 128x32 tile
    int r = e >> 5, c = e & 31;
    gload_lds16(base + (size_t)r * DM + k0 + c, lds + e);
  }
}

template <typename OutT>
__global__ __launch_bounds__(256, 4) void gemm_nt(const __bf16* __restrict__ A,
                                                  const __bf16* __restrict__ Wb,
                                                  OutT* __restrict__ Cb) {
  constexpr int K = DM, N = DM, NT = K / 32;
  __shared__ __bf16 As[2][128 * 32];
  __shared__ __bf16 Bs[2][128 * 32];

  const __bf16* Wp = Wb + (size_t)blockIdx.z * DD;
  OutT* Cp = Cb + (size_t)blockIdx.z * MD;

  // bijective XCD swizzle within each z-slice: nwg_xy = 8*128 = 1024 (%8==0)
  const int orig = blockIdx.y * 8 + blockIdx.x;
  const int sid = (orig & 7) * 128 + (orig >> 3);
  const int bx = sid & 7, by = sid >> 3;
  const int m0 = by * 128, n0 = bx * 128;

  const int t = threadIdx.x, lane = t & 63, wv = t >> 6;
  const int wr = wv >> 1, wc = wv & 1;          // 2 x 2 waves, 64x64 each
  const int lrow = lane & 15, koff = (lane >> 4) * 8;

  const __bf16* Abase = A + (size_t)m0 * K;
  const __bf16* Bbase = Wp + (size_t)n0 * K;

  f32x4 acc[4][4] = {};
  bf16x8 a[4], b[4];

  // prologue: stage kt0 into buf0
  stage_tile(Abase, As[0], 0, t);
  stage_tile(Bbase, Bs[0], 0, t);
  asm volatile("s_waitcnt vmcnt(0)\n\ts_barrier" ::: "memory");

#pragma unroll 1
  for (int kt = 0; kt < NT; ++kt) {
    const int cur = kt & 1, nxt = cur ^ 1;
    if (kt + 1 < NT) {
      stage_tile(Abase, As[nxt], (kt + 1) * 32, t);
      stage_tile(Bbase, Bs[nxt], (kt + 1) * 32, t);
    }
#pragma unroll
    for (int mf = 0; mf < 4; ++mf)
      a[mf] = *(const bf16x8*)&As[cur][(wr * 64 + mf * 16 + lrow) * 32 + koff];
#pragma unroll
    for (int nf = 0; nf < 4; ++nf)
      b[nf] = *(const bf16x8*)&Bs[cur][(wc * 64 + nf * 16 + lrow) * 32 + koff];
    __builtin_amdgcn_s_setprio(1);
#pragma unroll
    for (int mf = 0; mf < 4; ++mf)
#pragma unroll
      for (int nf = 0; nf < 4; ++nf)
        acc[mf][nf] = __builtin_amdgcn_mfma_f32_16x16x32_bf16(
            a[mf], b[nf], acc[mf][nf], 0, 0, 0);
    __builtin_amdgcn_s_setprio(0);
    asm volatile("s_waitcnt vmcnt(0) lgkmcnt(0)\n\ts_barrier" ::: "memory");
  }

  // epilogue: C/D layout col=lane&15, row=(lane>>4)*4+j
#pragma unroll
  for (int mf = 0; mf < 4; ++mf) {
    int r0 = m0 + wr * 64 + mf * 16 + (lane >> 4) * 4;
#pragma unroll
    for (int nf = 0; nf < 4; ++nf) {
      int c0 = n0 + wc * 64 + nf * 16 + (lane & 15);
#pragma unroll
      for (int j = 0; j < 4; ++j) {
        float v = acc[mf][nf][j];
        if constexpr (__is_same(OutT, float))
          Cp[(size_t)(r0 + j) * N + c0] = v;
        else
          Cp[(size_t)(r0 + j) * N + c0] = (__bf16)v;
      }
    }
  }
}

// ---- chunk sums: csum[c][chain] = sum_t lam^(31-t) v_t over chunk c ----
__global__ __launch_bounds__(256) void scan_sum(const __bf16* __restrict__ v,
                                                float* __restrict__ csum,
                                                const float* __restrict__ decay) {
  int tid = blockIdx.x * 256 + threadIdx.x;
  int dg = tid & 255;
  int b  = (tid >> 8) & 3;
  int c  = tid >> 10;
  int d0 = dg * 4;
  float lam = decay[((d0 >> 6) << 1) + 1];
  f32x4 s = {0.f, 0.f, 0.f, 0.f};
  size_t base = ((size_t)b * LSEQ + (size_t)c * CHUNK) * DM + d0;
  for (int t = 0; t < CHUNK; ++t) {
    bf16x4 vv = *(const bf16x4*)(v + base);
    f32x4 vf = {(float)vv[0], (float)vv[1], (float)vv[2], (float)vv[3]};
    s = lam * s + vf;
    base += DM;
  }
  *(f32x4*)(csum + (size_t)c * NCHAIN + b * DM + d0) = s;
}

// ---- pass2: carry[c][chain] = full state entering chunk c ----
__global__ __launch_bounds__(256) void scan2(const float* __restrict__ csum,
                                             float* __restrict__ carry,
                                             const float* __restrict__ decay) {
  int i = blockIdx.x * 256 + threadIdx.x;
  int ch0 = i * 4;
  int d0 = ch0 & (DM - 1);
  float lam = decay[((d0 >> 6) << 1) + 1];
  float l2 = lam * lam, l4 = l2 * l2, l8 = l4 * l4, l16 = l8 * l8;
  float lamC = l16 * l16;
  f32x4 cs = {0.f, 0.f, 0.f, 0.f};
  for (int c = 0; c < NCH; ++c) {
    *(f32x4*)(carry + (size_t)c * NCHAIN + ch0) = cs;
    f32x4 sm = *(const f32x4*)(csum + (size_t)c * NCHAIN + ch0);
    cs = lamC * cs + sm;
  }
}

// ---- fused per-chunk: exact scan (carry-seeded) + y=q*s + LN + silu gate ----
__global__ __launch_bounds__(256) void fuse_chunk(
    const __bf16* __restrict__ qb, const __bf16* __restrict__ vb,
    const __bf16* __restrict__ gb, const float* __restrict__ carry,
    const float* __restrict__ decay, const float* __restrict__ ln_g,
    const float* __restrict__ ln_b, __bf16* __restrict__ y2) {
  const int blk = blockIdx.x;
  const int b = blk >> 7, c = blk & 127;
  const int t = threadIdx.x, lane = t & 63, wv = t >> 6;
  const int d0 = t * 4;
  const float lam = decay[((d0 >> 6) << 1) + 1];
  f32x4 s = *(const f32x4*)(carry + (size_t)c * NCHAIN + b * DM + d0);
  const size_t base0 = ((size_t)b * LSEQ + (size_t)c * CHUNK) * DM + d0;

  __shared__ float sbs[2][32][4];
  __shared__ float stats[32][2];

  f32x4 y[32];
#pragma unroll
  for (int r = 0; r < 32; ++r) {
    size_t base = base0 + (size_t)r * DM;
    bf16x4 v4 = *(const bf16x4*)(vb + base);
    bf16x4 q4 = *(const bf16x4*)(qb + base);
    f32x4 vf = {(float)v4[0], (float)v4[1], (float)v4[2], (float)v4[3]};
    s = lam * s + vf;
    f32x4 yy;
    float su = 0.f, sq = 0.f;
#pragma unroll
    for (int i = 0; i < 4; ++i) {
      float val = (float)q4[i] * s[i];
      yy[i] = val; su += val; sq += val * val;
    }
    y[r] = yy;
#pragma unroll
    for (int o = 32; o > 0; o >>= 1) {
      su += __shfl_xor(su, o);
      sq += __shfl_xor(sq, o);
    }
    if (lane == 0) { sbs[0][r][wv] = su; sbs[1][r][wv] = sq; }
  }
  __syncthreads();
  if (t < 32) {
    float su = sbs[0][t][0] + sbs[0][t][1] + sbs[0][t][2] + sbs[0][t][3];
    float sq = sbs[1][t][0] + sbs[1][t][1] + sbs[1][t][2] + sbs[1][t][3];
    float mu = su * (1.0f / DM);
    float var = sq * (1.0f / DM) - mu * mu;
    stats[t][0] = mu;
    stats[t][1] = rsqrtf(fmaxf(var, 0.0f) + 1e-5f);
  }
  __syncthreads();

  f32x4 lg = *(const f32x4*)(ln_g + d0);
  f32x4 lb = *(const f32x4*)(ln_b + d0);
#pragma unroll
  for (int r = 0; r < 32; ++r) {
    size_t base = base0 + (size_t)r * DM;
    bf16x4 g4 = *(const bf16x4*)(gb + base);
    const float mu = stats[r][0], rstd = stats[r][1];
    bf16x4 o4;
#pragma unroll
    for (int i = 0; i < 4; ++i) {
      float gv = (float)g4[i];
      float gate = gv / (1.0f + __expf(-gv));
      o4[i] = (__bf16)(fmaf((y[r][i] - mu) * rstd, lg[i], lb[i]) * gate);
    }
    *(bf16x4*)(y2 + base) = o4;
  }
}

extern "C" void kernel_launch(void* const* d_in, const int* in_sizes, int n_in,
                              void* d_out, int out_size, void* d_ws, size_t ws_size,
                              hipStream_t stream) {
  const float* x     = (const float*)d_in[0];
  const float* decay = (const float*)d_in[3];
  const float* Wq    = (const float*)d_in[4];
  const float* Wv    = (const float*)d_in[5];
  const float* Wo    = (const float*)d_in[6];
  const float* Wg    = (const float*)d_in[7];
  const float* lng   = (const float*)d_in[8];
  const float* lnb   = (const float*)d_in[9];
  float* out = (float*)d_out;

  char* ws = (char*)d_ws;
  size_t off = 0;
  auto alloc = [&](size_t bytes) -> void* {
    void* p = ws + off;
    off += (bytes + 255) & ~(size_t)255;
    return p;
  };
  __bf16* xb   = (__bf16*)alloc(MD * 2);        // x in bf16
  __bf16* w4   = (__bf16*)alloc(4 * DD * 2);    // Wq|Wv|Wg|Wo in bf16
  __bf16* qvg  = (__bf16*)alloc(3 * MD * 2);    // q|v|g
  __bf16* y2b  = (__bf16*)alloc(MD * 2);        // post-LN*gate in bf16
  float*  csum = (float*)alloc((size_t)NCH * NCHAIN * 4);
  float*  cry  = (float*)alloc((size_t)NCH * NCHAIN * 4);

  cvt_bf16<<<(int)(MD / 1024), 256, 0, stream>>>(x, xb);
  cvt_w<<<dim3((unsigned)(DD / 1024), 1, 4), 256, 0, stream>>>(Wq, Wv, Wg, Wo, w4);

  gemm_nt<__bf16><<<dim3(8, MROWS / 128, 3), 256, 0, stream>>>(xb, w4, qvg);

  scan_sum<<<(BATCH * NCH * (DM / 4)) / 256, 256, 0, stream>>>(qvg + MD, csum, decay);
  scan2<<<(NCHAIN / 4) / 256, 256, 0, stream>>>(csum, cry, decay);

  fuse_chunk<<<BATCH * NCH, 256, 0, stream>>>(qvg, qvg + MD, qvg + 2 * MD, cry,
                                              decay, lng, lnb, y2b);

  gemm_nt<float><<<dim3(8, MROWS / 128, 1), 256, 0, stream>>>(y2b, w4 + 3 * DD, out);
}